// Round 2
// baseline (1064.200 us; speedup 1.0000x reference)
//
#include <hip/hip_runtime.h>
#include <hip/hip_bf16.h>
#include <cstdint>

#define D_MODEL 1024
#define D_FF    4096
#define NEXP    8
#define TOPK    2
#define TOKENS  8192                 // B*S
#define NPAIR   (TOKENS * TOPK)      // 16384
#define NPAD    (NPAIR + 128)        // 16512 (slack so tile staging stays in-bounds)

typedef __bf16 bf16x8 __attribute__((ext_vector_type(8)));
typedef float  f32x4  __attribute__((ext_vector_type(4)));

__device__ __forceinline__ unsigned short f2bf(float f) {
    unsigned int u = __float_as_uint(f);
    unsigned int r = (u + 0x7FFFu + ((u >> 16) & 1u)) >> 16;
    return (unsigned short)r;
}

__device__ __forceinline__ void lds_load16(void* lds, const void* g) {
    __builtin_amdgcn_global_load_lds(
        (const __attribute__((address_space(1))) void*)g,
        (__attribute__((address_space(3))) void*)lds, 16, 0, 0);
}

// tanh-form GELU: one v_exp_f32; saturates correctly at +/-inf; |err vs erf-gelu| < 3e-3
__device__ __forceinline__ float fast_gelu(float v) {
    float y2 = 1.5957691216f * (v + 0.044715f * v * v * v);   // 2*sqrt(2/pi)*(v+...)
    float t = 1.0f - 2.0f / (__expf(y2) + 1.0f);
    return 0.5f * v * (1.0f + t);
}

// ---------------- gating: logits -> softmax -> top2 -> renorm ----------------
__global__ __launch_bounds__(64) void gate_kernel(
        const float* __restrict__ x, const float* __restrict__ gw,
        int* __restrict__ tok_e, float* __restrict__ tok_w, int* __restrict__ cnt)
{
    const int t = blockIdx.x;
    const int lane = threadIdx.x;
    const float* xr = x + (size_t)t * D_MODEL;
    float xv[16];
#pragma unroll
    for (int i = 0; i < 16; ++i) xv[i] = xr[lane + 64 * i];
    float lg[NEXP];
#pragma unroll
    for (int e = 0; e < NEXP; ++e) {
        const float* g = gw + e * D_MODEL;
        float s = 0.f;
#pragma unroll
        for (int i = 0; i < 16; ++i) s += xv[i] * g[lane + 64 * i];
        for (int off = 32; off; off >>= 1) s += __shfl_down(s, off);
        lg[e] = s;
    }
    if (lane == 0) {
        float m = lg[0];
#pragma unroll
        for (int e = 1; e < NEXP; ++e) m = fmaxf(m, lg[e]);
        float ex[NEXP], S = 0.f;
#pragma unroll
        for (int e = 0; e < NEXP; ++e) { ex[e] = expf(lg[e] - m); S += ex[e]; }
        int i0 = 0; float p0 = ex[0];
#pragma unroll
        for (int e = 1; e < NEXP; ++e) if (ex[e] > p0) { p0 = ex[e]; i0 = e; }
        int i1 = -1; float p1 = -1.f;
#pragma unroll
        for (int e = 0; e < NEXP; ++e) if (e != i0 && ex[e] > p1) { p1 = ex[e]; i1 = e; }
        float q0 = p0 / S, q1 = p1 / S;
        float denom = q0 + q1 + 1e-9f;
        tok_e[2 * t] = i0; tok_e[2 * t + 1] = i1;
        tok_w[2 * t] = q0 / denom; tok_w[2 * t + 1] = q1 / denom;
        atomicAdd(&cnt[i0], 1); atomicAdd(&cnt[i1], 1);
    }
}

__global__ void offsets_kernel(const int* __restrict__ cnt, int* __restrict__ offs,
                               int* __restrict__ fill)
{
    if (threadIdx.x == 0 && blockIdx.x == 0) {
        int s = 0;
        for (int e = 0; e < NEXP; ++e) { offs[e] = s; fill[e] = s; s += cnt[e]; }
        offs[NEXP] = s;
    }
}

__global__ __launch_bounds__(256) void scatter_kernel(
        const int* __restrict__ tok_e, const float* __restrict__ tok_w,
        int* __restrict__ fill, int* __restrict__ pair_tok, float* __restrict__ pair_w)
{
    int t = blockIdx.x * 256 + threadIdx.x;
    if (t >= TOKENS) return;
#pragma unroll
    for (int k = 0; k < TOPK; ++k) {
        int e = tok_e[2 * t + k];
        int pos = atomicAdd(&fill[e], 1);
        pair_tok[pos] = t;
        pair_w[pos] = tok_w[2 * t + k];
    }
}

// ---------------- gather x rows per pair, convert to bf16 ----------------
__global__ __launch_bounds__(256) void gather_cvt(
        const float* __restrict__ x, const int* __restrict__ pair_tok,
        unsigned short* __restrict__ Xg)
{
    int p = blockIdx.x;
    int tok = pair_tok[p];
    const float4* src = (const float4*)(x + (size_t)tok * D_MODEL);
    ushort4* dst = (ushort4*)(Xg + (size_t)p * D_MODEL);
    float4 v = src[threadIdx.x];
    ushort4 o;
    o.x = f2bf(v.x); o.y = f2bf(v.y); o.z = f2bf(v.z); o.w = f2bf(v.w);
    dst[threadIdx.x] = o;
}

// ---------------- transpose + convert weights: fp32 [E][R][C] -> bf16 [E][C][R] ----
__global__ __launch_bounds__(256) void transpose_cvt(
        const float* __restrict__ in, unsigned short* __restrict__ out, int R, int C)
{
    __shared__ float tile[32][33];
    const int e = blockIdx.z;
    const int r0 = blockIdx.y * 32, c0 = blockIdx.x * 32;
    const float* src = in + (size_t)e * R * C;
    unsigned short* dst = out + (size_t)e * R * C;
    const int tx = threadIdx.x & 31, ty = threadIdx.x >> 5;   // ty 0..7
#pragma unroll
    for (int i = 0; i < 32; i += 8)
        tile[ty + i][tx] = src[(size_t)(r0 + ty + i) * C + (c0 + tx)];
    __syncthreads();
#pragma unroll
    for (int i = 0; i < 32; i += 8)
        dst[(size_t)(c0 + ty + i) * R + (r0 + tx)] = f2bf(tile[tx][ty + i]);
}

// ---------------- shared GEMM tile machinery (128x128, BK=32, double-buffered) ------
// Stage for K-step (K0) into statically-named LDS pair (AS,BS); LD = global row stride.
#define MOE_STAGE(AS, BS, K0, LD) \
    lds_load16(AS + t * 8,        ag + (K0)); \
    lds_load16(AS + 2048 + t * 8, ag + (size_t)64 * (LD) + (K0)); \
    lds_load16(BS + t * 8,        bg + (K0)); \
    lds_load16(BS + 2048 + t * 8, bg + (size_t)64 * (LD) + (K0));

#define MOE_COMPUTE(AS, BS) { \
    bf16x8 a_[4], b_[4]; \
    _Pragma("unroll") \
    for (int i_ = 0; i_ < 4; ++i_) { \
        a_[i_] = *(const bf16x8*)&AS[(wm * 64 + i_ * 16 + lm) * 32 + quad * 8]; \
        b_[i_] = *(const bf16x8*)&BS[(wn * 64 + i_ * 16 + lm) * 32 + quad * 8]; \
    } \
    _Pragma("unroll") \
    for (int i_ = 0; i_ < 4; ++i_) \
    _Pragma("unroll") \
    for (int j_ = 0; j_ < 4; ++j_) \
        c[i_][j_] = __builtin_amdgcn_mfma_f32_16x16x32_bf16(a_[i_], b_[j_], c[i_][j_], 0, 0, 0); }

// XCD-aware bijective swizzle: all n-tiles of one m-panel land on the SAME XCD
// (xcd = panel % 8), consecutively. Requires gridDim.y % 8 == 0.
// H/Xg m-panel then fetched once per XCD instead of once per n-tile's XCD (8x less
// HBM traffic for the activation operand); successive panels on an XCD (y, y+8) are
// same-expert -> weight panels reuse L2/L3.
#define MOE_SWIZZLE(XT, YT) \
    { int d_ = blockIdx.y * gridDim.x + blockIdx.x; \
      int xcd_ = d_ & 7, k_ = d_ >> 3; \
      XT = k_ % gridDim.x; \
      YT = (k_ / gridDim.x) * 8 + xcd_; }

// ---------------- GEMM1: H[p][f] = gelu(Xg[p] . w1t[e][f] + b1[e][f]) ----------------
__global__ __launch_bounds__(256, 2) void gemm1_kernel(
        const unsigned short* __restrict__ Xg, const unsigned short* __restrict__ w1t,
        const float* __restrict__ b1, const int* __restrict__ offs,
        unsigned short* __restrict__ H)
{
    int xt, yt;
    MOE_SWIZZLE(xt, yt)
    const int e = blockIdx.z;
    const int seg1 = offs[e + 1];
    const int row0 = offs[e] + yt * 128;
    if (row0 >= seg1) return;
    const int n0 = xt * 128;

    __shared__ __align__(16) unsigned short As0[128 * 32];
    __shared__ __align__(16) unsigned short As1[128 * 32];
    __shared__ __align__(16) unsigned short Bs0[128 * 32];
    __shared__ __align__(16) unsigned short Bs1[128 * 32];

    const int t = threadIdx.x;
    const int ca = (t & 3) * 8;
    const unsigned short* ag = Xg + (size_t)(row0 + (t >> 2)) * D_MODEL + ca;
    const unsigned short* bg = w1t + (size_t)e * D_FF * D_MODEL
                                   + (size_t)(n0 + (t >> 2)) * D_MODEL + ca;

    const int wave = t >> 6, lane = t & 63;
    const int wm = wave & 1, wn = wave >> 1;
    const int lm = lane & 15, quad = lane >> 4;

    f32x4 c[4][4] = {};

    MOE_STAGE(As0, Bs0, 0, D_MODEL)
    __syncthreads();
    for (int kt = 0; kt < D_MODEL; kt += 64) {
        // phase A: prefetch kt+32 into buf1, compute kt from buf0
        MOE_STAGE(As1, Bs1, kt + 32, D_MODEL)
        MOE_COMPUTE(As0, Bs0)
        __syncthreads();
        // phase B: prefetch kt+64 into buf0, compute kt+32 from buf1
        if (kt + 64 < D_MODEL) { MOE_STAGE(As0, Bs0, kt + 64, D_MODEL) }
        MOE_COMPUTE(As1, Bs1)
        __syncthreads();
    }

    float b1v[4];
#pragma unroll
    for (int j = 0; j < 4; ++j)
        b1v[j] = b1[e * D_FF + n0 + wn * 64 + j * 16 + lm];
#pragma unroll
    for (int i = 0; i < 4; ++i) {
#pragma unroll
        for (int r = 0; r < 4; ++r) {
            int gm = row0 + wm * 64 + i * 16 + quad * 4 + r;
            if (gm < seg1) {
#pragma unroll
                for (int j = 0; j < 4; ++j) {
                    int gn = n0 + wn * 64 + j * 16 + lm;
                    float v = c[i][j][r] + b1v[j];
                    H[(size_t)gm * D_FF + gn] = f2bf(fast_gelu(v));
                }
            }
        }
    }
}

// ---------------- GEMM2: out[tok] += w_p * (H[p] . w2t[e][d] + b2[e][d]) ----------------
__global__ __launch_bounds__(256, 2) void gemm2_kernel(
        const unsigned short* __restrict__ H, const unsigned short* __restrict__ w2t,
        const float* __restrict__ b2, const int* __restrict__ offs,
        const int* __restrict__ pair_tok, const float* __restrict__ pair_w,
        float* __restrict__ out)
{
    int xt, yt;
    MOE_SWIZZLE(xt, yt)
    const int e = blockIdx.z;
    const int seg1 = offs[e + 1];
    const int row0 = offs[e] + yt * 128;
    if (row0 >= seg1) return;
    const int n0 = xt * 128;

    __shared__ __align__(16) unsigned short As0[128 * 32];
    __shared__ __align__(16) unsigned short As1[128 * 32];
    __shared__ __align__(16) unsigned short Bs0[128 * 32];
    __shared__ __align__(16) unsigned short Bs1[128 * 32];

    const int t = threadIdx.x;
    const int ca = (t & 3) * 8;
    const unsigned short* ag = H + (size_t)(row0 + (t >> 2)) * D_FF + ca;
    const unsigned short* bg = w2t + (size_t)e * D_MODEL * D_FF
                                   + (size_t)(n0 + (t >> 2)) * D_FF + ca;

    const int wave = t >> 6, lane = t & 63;
    const int wm = wave & 1, wn = wave >> 1;
    const int lm = lane & 15, quad = lane >> 4;

    f32x4 c[4][4] = {};

    MOE_STAGE(As0, Bs0, 0, D_FF)
    __syncthreads();
    for (int kt = 0; kt < D_FF; kt += 64) {
        MOE_STAGE(As1, Bs1, kt + 32, D_FF)
        MOE_COMPUTE(As0, Bs0)
        __syncthreads();
        if (kt + 64 < D_FF) { MOE_STAGE(As0, Bs0, kt + 64, D_FF) }
        MOE_COMPUTE(As1, Bs1)
        __syncthreads();
    }

    float b2v[4];
#pragma unroll
    for (int j = 0; j < 4; ++j)
        b2v[j] = b2[e * D_MODEL + n0 + wn * 64 + j * 16 + lm];
#pragma unroll
    for (int i = 0; i < 4; ++i) {
#pragma unroll
        for (int r = 0; r < 4; ++r) {
            int gm = row0 + wm * 64 + i * 16 + quad * 4 + r;
            if (gm < seg1) {
                int tok = pair_tok[gm];
                float wgt = pair_w[gm];
#pragma unroll
                for (int j = 0; j < 4; ++j) {
                    int gn = n0 + wn * 64 + j * 16 + lm;
                    float v = (c[i][j][r] + b2v[j]) * wgt;
                    atomicAdd(&out[(size_t)tok * D_MODEL + gn], v);
                }
            }
        }
    }
}

// ---------------- launcher ----------------
// Workspace: single 64 MiB WT buffer reused for w1^T then w2^T (stream-serialized).
// Total ~225.5 MiB; staying under input total (~288 MiB) — round-1 overflow lesson.
extern "C" void kernel_launch(void* const* d_in, const int* in_sizes, int n_in,
                              void* d_out, int out_size, void* d_ws, size_t ws_size,
                              hipStream_t stream)
{
    const float* x      = (const float*)d_in[0];
    const float* gate_w = (const float*)d_in[1];
    const float* w1     = (const float*)d_in[2];
    const float* b1     = (const float*)d_in[3];
    const float* w2     = (const float*)d_in[4];
    const float* b2     = (const float*)d_in[5];
    float* out = (float*)d_out;

    char* ws = (char*)d_ws;
    const size_t WT_OFF   = 0;                                              // 64 MiB (shared w1t/w2t)
    const size_t XG_OFF   = WT_OFF + (size_t)NEXP * D_FF * D_MODEL * 2;
    const size_t H_OFF    = XG_OFF + (size_t)NPAD * D_MODEL * 2;
    const size_t PTOK_OFF = H_OFF + (size_t)NPAD * D_FF * 2;
    const size_t PW_OFF   = PTOK_OFF + (size_t)NPAD * 4;
    const size_t TOKE_OFF = PW_OFF + (size_t)NPAD * 4;
    const size_t TOKW_OFF = TOKE_OFF + (size_t)NPAIR * 4;
    const size_t CNT_OFF  = TOKW_OFF + (size_t)NPAIR * 4;

    unsigned short* wt  = (unsigned short*)(ws + WT_OFF);
    unsigned short* Xg  = (unsigned short*)(ws + XG_OFF);
    unsigned short* H   = (unsigned short*)(ws + H_OFF);
    int*   pair_tok = (int*)(ws + PTOK_OFF);
    float* pair_w   = (float*)(ws + PW_OFF);
    int*   tok_e    = (int*)(ws + TOKE_OFF);
    float* tok_w    = (float*)(ws + TOKW_OFF);
    int*   cnt      = (int*)(ws + CNT_OFF);   // 8 ints
    int*   fill     = cnt + 8;                // 8 ints
    int*   offs     = cnt + 16;               // 9 ints

    hipMemsetAsync(cnt, 0, 64, stream);
    hipMemsetAsync(out, 0, (size_t)out_size * sizeof(float), stream);

    gate_kernel<<<TOKENS, 64, 0, stream>>>(x, gate_w, tok_e, tok_w, cnt);
    offsets_kernel<<<1, 64, 0, stream>>>(cnt, offs, fill);
    scatter_kernel<<<TOKENS / 256, 256, 0, stream>>>(tok_e, tok_w, fill, pair_tok, pair_w);
    gather_cvt<<<NPAIR, 256, 0, stream>>>(x, pair_tok, Xg);

    // w1^T into WT, GEMM1, then w2^T into the SAME WT buffer, GEMM2.
    transpose_cvt<<<dim3(D_FF / 32, D_MODEL / 32, NEXP), 256, 0, stream>>>(w1, wt, D_MODEL, D_FF);
    gemm1_kernel<<<dim3(D_FF / 128, TOKENS / 128, NEXP), 256, 0, stream>>>(Xg, wt, b1, offs, H);
    transpose_cvt<<<dim3(D_MODEL / 32, D_FF / 32, NEXP), 256, 0, stream>>>(w2, wt, D_FF, D_MODEL);
    gemm2_kernel<<<dim3(D_MODEL / 128, TOKENS / 128, NEXP), 256, 0, stream>>>(H, wt, b2, offs, pair_tok, pair_w, out);
}

// Round 4
// 833.259 us; speedup vs baseline: 1.2772x; 1.2772x over previous
//
#include <hip/hip_runtime.h>
#include <hip/hip_bf16.h>
#include <cstdint>

#define D_MODEL 1024
#define D_FF    4096
#define NEXP    8
#define TOPK    2
#define TOKENS  8192                 // B*S
#define NPAIR   (TOKENS * TOPK)      // 16384
#define NPAD    (NPAIR + 128)        // 16512 (slack so tile staging stays in-bounds)

typedef __bf16 bf16x8 __attribute__((ext_vector_type(8)));
typedef float  f32x4  __attribute__((ext_vector_type(4)));

__device__ __forceinline__ unsigned short f2bf(float f) {
    unsigned int u = __float_as_uint(f);
    unsigned int r = (u + 0x7FFFu + ((u >> 16) & 1u)) >> 16;
    return (unsigned short)r;
}

__device__ __forceinline__ void lds_load16(void* lds, const void* g) {
    __builtin_amdgcn_global_load_lds(
        (const __attribute__((address_space(1))) void*)g,
        (__attribute__((address_space(3))) void*)lds, 16, 0, 0);
}

// tanh-form GELU: one v_exp_f32; saturates correctly at +/-inf; |err vs erf-gelu| < 3e-3
__device__ __forceinline__ float fast_gelu(float v) {
    float y2 = 1.5957691216f * (v + 0.044715f * v * v * v);   // 2*sqrt(2/pi)*(v+...)
    float t = 1.0f - 2.0f / (__expf(y2) + 1.0f);
    return 0.5f * v * (1.0f + t);
}

// ---------------- gating: logits -> softmax -> top2 -> renorm (no counting) ---------
__global__ __launch_bounds__(64) void gate_kernel(
        const float* __restrict__ x, const float* __restrict__ gw,
        int* __restrict__ tok_e, float* __restrict__ tok_w)
{
    const int t = blockIdx.x;
    const int lane = threadIdx.x;
    const float* xr = x + (size_t)t * D_MODEL;
    float xv[16];
#pragma unroll
    for (int i = 0; i < 16; ++i) xv[i] = xr[lane + 64 * i];
    float lg[NEXP];
#pragma unroll
    for (int e = 0; e < NEXP; ++e) {
        const float* g = gw + e * D_MODEL;
        float s = 0.f;
#pragma unroll
        for (int i = 0; i < 16; ++i) s += xv[i] * g[lane + 64 * i];
        for (int off = 32; off; off >>= 1) s += __shfl_down(s, off);
        lg[e] = s;
    }
    if (lane == 0) {
        float m = lg[0];
#pragma unroll
        for (int e = 1; e < NEXP; ++e) m = fmaxf(m, lg[e]);
        float ex[NEXP], S = 0.f;
#pragma unroll
        for (int e = 0; e < NEXP; ++e) { ex[e] = expf(lg[e] - m); S += ex[e]; }
        int i0 = 0; float p0 = ex[0];
#pragma unroll
        for (int e = 1; e < NEXP; ++e) if (ex[e] > p0) { p0 = ex[e]; i0 = e; }
        int i1 = -1; float p1 = -1.f;
#pragma unroll
        for (int e = 0; e < NEXP; ++e) if (e != i0 && ex[e] > p1) { p1 = ex[e]; i1 = e; }
        float q0 = p0 / S, q1 = p1 / S;
        float denom = q0 + q1 + 1e-9f;
        tok_e[2 * t] = i0; tok_e[2 * t + 1] = i1;
        tok_w[2 * t] = q0 / denom; tok_w[2 * t + 1] = q1 / denom;
    }
}

// ---------------- count: LDS histogram, 8 global atomics per block ----------------
__global__ __launch_bounds__(256) void count_kernel(
        const int* __restrict__ tok_e, int* __restrict__ cnt)
{
    __shared__ int lc[NEXP];
    const int t = blockIdx.x * 256 + threadIdx.x;
    if (threadIdx.x < NEXP) lc[threadIdx.x] = 0;
    __syncthreads();
    atomicAdd(&lc[tok_e[2 * t]], 1);
    atomicAdd(&lc[tok_e[2 * t + 1]], 1);
    __syncthreads();
    if (threadIdx.x < NEXP) atomicAdd(&cnt[threadIdx.x], lc[threadIdx.x]);
}

__global__ void offsets_kernel(const int* __restrict__ cnt, int* __restrict__ offs,
                               int* __restrict__ fill)
{
    if (threadIdx.x == 0 && blockIdx.x == 0) {
        int s = 0;
        for (int e = 0; e < NEXP; ++e) { offs[e] = s; fill[e] = s; s += cnt[e]; }
        offs[NEXP] = s;
    }
}

// ---------------- scatter: LDS rank + one chunk-reservation atomic per expert ------
__global__ __launch_bounds__(256) void scatter2_kernel(
        const int* __restrict__ tok_e, const float* __restrict__ tok_w,
        int* __restrict__ fill, int* __restrict__ pair_tok, float* __restrict__ pair_w)
{
    __shared__ int lc[NEXP], lbase[NEXP];
    const int t = blockIdx.x * 256 + threadIdx.x;
    if (threadIdx.x < NEXP) lc[threadIdx.x] = 0;
    __syncthreads();
    const int e0 = tok_e[2 * t], e1 = tok_e[2 * t + 1];
    const int r0 = atomicAdd(&lc[e0], 1);
    const int r1 = atomicAdd(&lc[e1], 1);
    __syncthreads();
    if (threadIdx.x < NEXP)
        lbase[threadIdx.x] = atomicAdd(&fill[threadIdx.x], lc[threadIdx.x]);
    __syncthreads();
    const int p0 = lbase[e0] + r0, p1 = lbase[e1] + r1;
    pair_tok[p0] = t; pair_w[p0] = tok_w[2 * t];
    pair_tok[p1] = t; pair_w[p1] = tok_w[2 * t + 1];
}

// ---------------- gather x rows per pair, convert to bf16 ----------------
__global__ __launch_bounds__(256) void gather_cvt(
        const float* __restrict__ x, const int* __restrict__ pair_tok,
        unsigned short* __restrict__ Xg)
{
    int p = blockIdx.x;
    int tok = pair_tok[p];
    const float4* src = (const float4*)(x + (size_t)tok * D_MODEL);
    ushort4* dst = (ushort4*)(Xg + (size_t)p * D_MODEL);
    float4 v = src[threadIdx.x];
    ushort4 o;
    o.x = f2bf(v.x); o.y = f2bf(v.y); o.z = f2bf(v.z); o.w = f2bf(v.w);
    dst[threadIdx.x] = o;
}

// ---------------- transpose + convert weights: fp32 [E][R][C] -> bf16 [E][C][R] ----
__global__ __launch_bounds__(256) void transpose_cvt(
        const float* __restrict__ in, unsigned short* __restrict__ out, int R, int C)
{
    __shared__ float tile[32][33];
    const int e = blockIdx.z;
    const int r0 = blockIdx.y * 32, c0 = blockIdx.x * 32;
    const float* src = in + (size_t)e * R * C;
    unsigned short* dst = out + (size_t)e * R * C;
    const int tx = threadIdx.x & 31, ty = threadIdx.x >> 5;   // ty 0..7
#pragma unroll
    for (int i = 0; i < 32; i += 8)
        tile[ty + i][tx] = src[(size_t)(r0 + ty + i) * C + (c0 + tx)];
    __syncthreads();
#pragma unroll
    for (int i = 0; i < 32; i += 8)
        dst[(size_t)(c0 + ty + i) * R + (r0 + tx)] = f2bf(tile[tx][ty + i]);
}

// ---------------- GEMM tile machinery: 128x128, BK=32, TRIPLE-buffered -------------
// T4 counted-vmcnt pipeline: stage tile t+2 while computing tile t; raw s_barrier
// (no vmcnt drain); vmcnt(8) leaves tiles t+1,t+2 (4 loads each) in flight.
// T2 XOR-swizzle: LDS 16B-chunk column j holds global chunk j ^ ((row>>1)&3).
// Write side realized by pre-swizzling the GLOBAL source column (global_load_lds
// writes linearly, rule #21); read side XORs the quad: both keys equal ((row>>1)&3).
// Per 16-lane ds_read_b128 group: each bank-quad gets 2 lanes (2-way = free, m136).
// Rotation pointers named sa*/sb* — must NOT shadow kernel params (R3 compile fail).
#define MOE_STAGE3(PA, PB, K0, LD) \
    lds_load16(PA + t * 8,        ag + (K0)); \
    lds_load16(PA + 2048 + t * 8, ag + (size_t)64 * (LD) + (K0)); \
    lds_load16(PB + t * 8,        bg + (K0)); \
    lds_load16(PB + 2048 + t * 8, bg + (size_t)64 * (LD) + (K0));

#define MOE_COMPUTE3(PA, PB) { \
    bf16x8 a_[4], b_[4]; \
    _Pragma("unroll") \
    for (int i_ = 0; i_ < 4; ++i_) { \
        a_[i_] = *(const bf16x8*)&PA[(wm * 64 + i_ * 16 + lm) * 32 + qs8]; \
        b_[i_] = *(const bf16x8*)&PB[(wn * 64 + i_ * 16 + lm) * 32 + qs8]; \
    } \
    __builtin_amdgcn_s_setprio(1); \
    _Pragma("unroll") \
    for (int i_ = 0; i_ < 4; ++i_) \
    _Pragma("unroll") \
    for (int j_ = 0; j_ < 4; ++j_) \
        c[i_][j_] = __builtin_amdgcn_mfma_f32_16x16x32_bf16(a_[i_], b_[j_], c[i_][j_], 0, 0, 0); \
    __builtin_amdgcn_s_setprio(0); }

// Pipelined K-loop over tiles of BK=32 (needs KTOT/32 >= 3), buffers rotate.
#define MOE_KLOOP(KTOT, LD) \
    MOE_STAGE3(sa0, sb0, 0, LD) \
    MOE_STAGE3(sa1, sb1, 32, LD) \
    for (int kt = 0; kt < (KTOT) - 64; kt += 32) { \
        MOE_STAGE3(sa2, sb2, kt + 64, LD) \
        asm volatile("s_waitcnt vmcnt(8)" ::: "memory"); \
        __builtin_amdgcn_s_barrier(); \
        MOE_COMPUTE3(sa0, sb0) \
        __builtin_amdgcn_s_barrier(); \
        unsigned short* tA_ = sa0; sa0 = sa1; sa1 = sa2; sa2 = tA_; \
        unsigned short* tB_ = sb0; sb0 = sb1; sb1 = sb2; sb2 = tB_; \
    } \
    asm volatile("s_waitcnt vmcnt(4)" ::: "memory"); \
    __builtin_amdgcn_s_barrier(); \
    MOE_COMPUTE3(sa0, sb0) \
    asm volatile("s_waitcnt vmcnt(0)" ::: "memory"); \
    __builtin_amdgcn_s_barrier(); \
    MOE_COMPUTE3(sa1, sb1)

// XCD-aware bijective swizzle (T1): all n-tiles of one m-panel land on the SAME XCD.
#define MOE_SWIZZLE(XT, YT) \
    { int d_ = blockIdx.y * gridDim.x + blockIdx.x; \
      int xcd_ = d_ & 7, k_ = d_ >> 3; \
      XT = k_ % gridDim.x; \
      YT = (k_ / gridDim.x) * 8 + xcd_; }

// ---------------- GEMM1: H[p][f] = gelu(Xg[p] . w1t[e][f] + b1[e][f]) ----------------
__global__ __launch_bounds__(256, 3) void gemm1_kernel(
        const unsigned short* __restrict__ Xg, const unsigned short* __restrict__ w1t,
        const float* __restrict__ b1, const int* __restrict__ offs,
        unsigned short* __restrict__ H)
{
    int xt, yt;
    MOE_SWIZZLE(xt, yt)
    const int e = blockIdx.z;
    const int seg1 = offs[e + 1];
    const int row0 = offs[e] + yt * 128;
    if (row0 >= seg1) return;
    const int n0 = xt * 128;

    __shared__ __align__(16) unsigned short SA[3 * 128 * 32];
    __shared__ __align__(16) unsigned short SB[3 * 128 * 32];
    unsigned short *sa0 = SA, *sa1 = SA + 4096, *sa2 = SA + 8192;
    unsigned short *sb0 = SB, *sb1 = SB + 4096, *sb2 = SB + 8192;

    const int t = threadIdx.x;
    const int ca = (((t & 3) ^ ((t >> 3) & 3))) * 8;   // pre-swizzled source column
    const unsigned short* ag = Xg + (size_t)(row0 + (t >> 2)) * D_MODEL + ca;
    const unsigned short* bg = w1t + (size_t)e * D_FF * D_MODEL
                                   + (size_t)(n0 + (t >> 2)) * D_MODEL + ca;

    const int wave = t >> 6, lane = t & 63;
    const int wm = wave & 1, wn = wave >> 1;
    const int lm = lane & 15, quad = lane >> 4;
    const int qs8 = (quad ^ ((lm >> 1) & 3)) * 8;      // swizzled read column

    f32x4 c[4][4] = {};

    MOE_KLOOP(D_MODEL, D_MODEL)

    float bb[4];
#pragma unroll
    for (int j = 0; j < 4; ++j)
        bb[j] = b1[e * D_FF + n0 + wn * 64 + j * 16 + lm];
#pragma unroll
    for (int i = 0; i < 4; ++i) {
#pragma unroll
        for (int r = 0; r < 4; ++r) {
            int gm = row0 + wm * 64 + i * 16 + quad * 4 + r;
            if (gm < seg1) {
#pragma unroll
                for (int j = 0; j < 4; ++j) {
                    int gn = n0 + wn * 64 + j * 16 + lm;
                    float v = c[i][j][r] + bb[j];
                    H[(size_t)gm * D_FF + gn] = f2bf(fast_gelu(v));
                }
            }
        }
    }
}

// ---------------- GEMM2: out[tok] += w_p * (H[p] . w2t[e][d] + b2[e][d]) ------------
__global__ __launch_bounds__(256, 3) void gemm2_kernel(
        const unsigned short* __restrict__ H, const unsigned short* __restrict__ w2t,
        const float* __restrict__ b2, const int* __restrict__ offs,
        const int* __restrict__ pair_tok, const float* __restrict__ pair_w,
        float* __restrict__ out)
{
    int xt, yt;
    MOE_SWIZZLE(xt, yt)
    const int e = blockIdx.z;
    const int seg1 = offs[e + 1];
    const int row0 = offs[e] + yt * 128;
    if (row0 >= seg1) return;
    const int n0 = xt * 128;

    __shared__ __align__(16) unsigned short SA[3 * 128 * 32];
    __shared__ __align__(16) unsigned short SB[3 * 128 * 32];
    unsigned short *sa0 = SA, *sa1 = SA + 4096, *sa2 = SA + 8192;
    unsigned short *sb0 = SB, *sb1 = SB + 4096, *sb2 = SB + 8192;

    const int t = threadIdx.x;
    const int ca = (((t & 3) ^ ((t >> 3) & 3))) * 8;
    const unsigned short* ag = H + (size_t)(row0 + (t >> 2)) * D_FF + ca;
    const unsigned short* bg = w2t + (size_t)e * D_MODEL * D_FF
                                   + (size_t)(n0 + (t >> 2)) * D_FF + ca;

    const int wave = t >> 6, lane = t & 63;
    const int wm = wave & 1, wn = wave >> 1;
    const int lm = lane & 15, quad = lane >> 4;
    const int qs8 = (quad ^ ((lm >> 1) & 3)) * 8;

    f32x4 c[4][4] = {};

    MOE_KLOOP(D_FF, D_FF)

    float bb[4];
#pragma unroll
    for (int j = 0; j < 4; ++j)
        bb[j] = b2[e * D_MODEL + n0 + wn * 64 + j * 16 + lm];
#pragma unroll
    for (int i = 0; i < 4; ++i) {
#pragma unroll
        for (int r = 0; r < 4; ++r) {
            int gm = row0 + wm * 64 + i * 16 + quad * 4 + r;
            if (gm < seg1) {
                int tok = pair_tok[gm];
                float wgt = pair_w[gm];
#pragma unroll
                for (int j = 0; j < 4; ++j) {
                    int gn = n0 + wn * 64 + j * 16 + lm;
                    float v = (c[i][j][r] + bb[j]) * wgt;
                    atomicAdd(&out[(size_t)tok * D_MODEL + gn], v);
                }
            }
        }
    }
}

// ---------------- launcher ----------------
extern "C" void kernel_launch(void* const* d_in, const int* in_sizes, int n_in,
                              void* d_out, int out_size, void* d_ws, size_t ws_size,
                              hipStream_t stream)
{
    const float* x      = (const float*)d_in[0];
    const float* gate_w = (const float*)d_in[1];
    const float* w1     = (const float*)d_in[2];
    const float* b1     = (const float*)d_in[3];
    const float* w2     = (const float*)d_in[4];
    const float* b2     = (const float*)d_in[5];
    float* out = (float*)d_out;

    char* ws = (char*)d_ws;
    const size_t WT_OFF   = 0;                                              // 64 MiB (shared w1t/w2t)
    const size_t XG_OFF   = WT_OFF + (size_t)NEXP * D_FF * D_MODEL * 2;
    const size_t H_OFF    = XG_OFF + (size_t)NPAD * D_MODEL * 2;
    const size_t PTOK_OFF = H_OFF + (size_t)NPAD * D_FF * 2;
    const size_t PW_OFF   = PTOK_OFF + (size_t)NPAD * 4;
    const size_t TOKE_OFF = PW_OFF + (size_t)NPAD * 4;
    const size_t TOKW_OFF = TOKE_OFF + (size_t)NPAIR * 4;
    const size_t CNT_OFF  = TOKW_OFF + (size_t)NPAIR * 4;

    unsigned short* wt  = (unsigned short*)(ws + WT_OFF);
    unsigned short* Xg  = (unsigned short*)(ws + XG_OFF);
    unsigned short* H   = (unsigned short*)(ws + H_OFF);
    int*   pair_tok = (int*)(ws + PTOK_OFF);
    float* pair_w   = (float*)(ws + PW_OFF);
    int*   tok_e    = (int*)(ws + TOKE_OFF);
    float* tok_w    = (float*)(ws + TOKW_OFF);
    int*   cnt      = (int*)(ws + CNT_OFF);   // 8 ints
    int*   fill     = cnt + 8;                // 8 ints
    int*   offs     = cnt + 16;               // 9 ints

    (void)hipMemsetAsync(cnt, 0, 64, stream);
    (void)hipMemsetAsync(out, 0, (size_t)out_size * sizeof(float), stream);

    gate_kernel<<<TOKENS, 64, 0, stream>>>(x, gate_w, tok_e, tok_w);
    count_kernel<<<TOKENS / 256, 256, 0, stream>>>(tok_e, cnt);
    offsets_kernel<<<1, 64, 0, stream>>>(cnt, offs, fill);
    scatter2_kernel<<<TOKENS / 256, 256, 0, stream>>>(tok_e, tok_w, fill, pair_tok, pair_w);
    gather_cvt<<<NPAIR, 256, 0, stream>>>(x, pair_tok, Xg);

    // w1^T into WT, GEMM1, then w2^T into the SAME WT buffer, GEMM2.
    transpose_cvt<<<dim3(D_FF / 32, D_MODEL / 32, NEXP), 256, 0, stream>>>(w1, wt, D_MODEL, D_FF);
    gemm1_kernel<<<dim3(D_FF / 128, TOKENS / 128, NEXP), 256, 0, stream>>>(Xg, wt, b1, offs, H);
    transpose_cvt<<<dim3(D_MODEL / 32, D_FF / 32, NEXP), 256, 0, stream>>>(w2, wt, D_FF, D_MODEL);
    gemm2_kernel<<<dim3(D_MODEL / 128, TOKENS / 128, NEXP), 256, 0, stream>>>(H, wt, b2, offs, pair_tok, pair_w, out);
}